// Round 7
// baseline (1384.354 us; speedup 1.0000x reference)
//
#include <hip/hip_runtime.h>
#include <hip/hip_bf16.h>

#define E_TOTAL 500000
#define NTILES ((E_TOTAL + 63) / 64)   // 7813
#define NBLOCKS 512

typedef __attribute__((ext_vector_type(8))) short bf16x8;
typedef __attribute__((ext_vector_type(4))) float f32x4;

// D = A*B + C ; A rows -> C rows (features), B cols -> C cols (edges)
#define MFMA(a, b, c) __builtin_amdgcn_mfma_f32_16x16x32_bf16((a), (b), (c), 0, 0, 0)

// Barrier with LDS-only drain: leaves global loads/stores in flight (T4 essence).
// Correct because no intra-block communication goes through global memory.
__device__ __forceinline__ void lbar() {
    asm volatile("s_waitcnt lgkmcnt(0)" ::: "memory");
    __builtin_amdgcn_s_barrier();
}

__device__ __forceinline__ unsigned short f2b(float f) {
    return __builtin_bit_cast(unsigned short, __float2bfloat16(f));
}
__device__ __forceinline__ float b2f(unsigned short s) {
    return __bfloat162float(__builtin_bit_cast(__hip_bfloat16, s));
}
__device__ __forceinline__ float sigm(float x) { return 1.f / (1.f + __expf(-x)); }
__device__ __forceinline__ float tanh_fast(float x) {
    float t = __expf(-2.f * x);
    return (1.f - t) / (1.f + t);
}
// XOR-swizzled LDS address (T2): spreads 8 consecutive rows over 8 16B slots.
__device__ __forceinline__ char* swzp(void* base, int row, int rowBytes, int colByte) {
    return (char*)base + row * rowBytes + (colByte ^ ((row & 7) << 4));
}

// f32 -> bf16 weight pre-conversion into workspace (runs every call; cheap).
__global__ void wconv_kernel(const float* __restrict__ W1, const float* __restrict__ Wih,
                             const float* __restrict__ Whh, const float* __restrict__ Wx,
                             unsigned short* __restrict__ out) {
    int i = blockIdx.x * 256 + threadIdx.x;
    if (i >= 155648) return;
    float v;
    if      (i < 49152)  v = W1[i];
    else if (i < 98304)  v = Wih[i - 49152];
    else if (i < 147456) v = Whh[i - 98304];
    else                 v = Wx[i - 147456];
    out[i] = f2b(v);
}

// LDS 71680 B. All tiles XOR-swizzled, pad-free strides.
struct Smem {
    union {
        unsigned short x1[64][384];                       // 49152, staging -> GEMM1
        struct { unsigned short y[64][128];               // [0,16384)   GEMM1-out -> GRU
                 unsigned short hnew[64][128]; } p;       // [16384,32768) GRU-out -> GEMM3/hout
        float xo[64][64];                                 // [0,16384) GEMM3 staging (aliases y)
    } u;
    unsigned short hbf[64][128];                          // 16384, h tile bf16
    float lns[64][12];                                    // 3072
    float ln2[64][12];                                    // 3072
};

__global__ __launch_bounds__(512, 1) void edge_model_kernel(
    const float* __restrict__ src, const float* __restrict__ dst,
    const float* __restrict__ eat, const float* __restrict__ hin,
    const float* __restrict__ u, const int* __restrict__ batch,
    const float* __restrict__ winding,
    const float* __restrict__ Ww, const float* __restrict__ bw,
    const float* __restrict__ gw, const float* __restrict__ betaw,
    const float* __restrict__ b1, const float* __restrict__ g1,
    const float* __restrict__ beta1,
    const float* __restrict__ bih, const float* __restrict__ bhh,
    const float* __restrict__ bx,
    const unsigned short* __restrict__ W1bf, const unsigned short* __restrict__ Wihbf,
    const unsigned short* __restrict__ Whhbf, const unsigned short* __restrict__ Wxbf,
    float* __restrict__ xout, float* __restrict__ hout)
{
    __shared__ Smem sm;
    const int tid  = threadIdx.x;
    const int wave = tid >> 6;        // 0..7; owns FEATURE rows [16w,16w+16)
    const int lane = tid & 63;
    const int lhi  = lane >> 4;       // 0..3
    const int llo  = lane & 15;       // 0..15
    const int fb   = wave * 16 + lhi * 4;   // 4-feature base (feature = fb + r)
    const int wrow = wave * 16 + llo;       // weight row for A-fragments

    // ---- loop-invariant params hoisted to registers ----
    const float4 b1q  = *(const float4*)&b1[fb];
    const float4 g1q  = *(const float4*)&g1[fb];
    const float4 be1q = *(const float4*)&beta1[fb];
    const float4 biq0 = *(const float4*)&bih[fb];
    const float4 biq1 = *(const float4*)&bih[128 + fb];
    const float4 biq2 = *(const float4*)&bih[256 + fb];
    const float4 bhq0 = *(const float4*)&bhh[fb];
    const float4 bhq1 = *(const float4*)&bhh[128 + fb];
    const float4 bhq2 = *(const float4*)&bhh[256 + fb];
    const float4 bxq  = *(const float4*)&bx[fb];

    // ---- cross-tile prefetch registers ----
    float4 pA[2], pB[2], pC[2], pD[2];   // src/dst/eat/u[batch]
    float4 pH[4];                        // h tile
    float  pw0, pw1;                     // winding

    auto issue_loads = [&](int T) {
        size_t b = (size_t)T * 64;
        #pragma unroll
        for (int it = 0; it < 2; ++it) {
            int q = it * 512 + tid; int row = q >> 4; int c4 = (q & 15) << 2;
            size_t e = b + row; if (e >= E_TOTAL) e = E_TOTAL - 1;
            pA[it] = *(const float4*)(src + e * 64 + c4);
            pB[it] = *(const float4*)(dst + e * 64 + c4);
            pC[it] = *(const float4*)(eat + e * 64 + c4);
            int bi = batch[e];
            pD[it] = *(const float4*)(u + (size_t)bi * 64 + c4);
        }
        #pragma unroll
        for (int it = 0; it < 4; ++it) {
            int q = it * 512 + tid; int row = q >> 5; int c4 = (q & 31) << 2;
            size_t e = b + row; if (e >= E_TOTAL) e = E_TOTAL - 1;
            pH[it] = *(const float4*)(hin + e * 128 + c4);
        }
        {
            int row = tid >> 3;
            size_t e = b + row; if (e >= E_TOTAL) e = E_TOTAL - 1;
            pw0 = winding[e * 2]; pw1 = winding[e * 2 + 1];
        }
    };

    issue_loads(blockIdx.x);   // prologue prefetch (only exposed latency)

    for (int tile = blockIdx.x; tile < NTILES; tile += NBLOCKS) {
        const size_t e0 = (size_t)tile * 64;

        // ---------------- Phase A: write prefetched regs to LDS (swizzled) ----------------
        #pragma unroll
        for (int it = 0; it < 2; ++it) {
            int q   = it * 512 + tid;
            int row = q >> 4;
            int c4  = (q & 15) << 2;
            ushort4 pa; pa.x=f2b(pA[it].x); pa.y=f2b(pA[it].y); pa.z=f2b(pA[it].z); pa.w=f2b(pA[it].w);
            ushort4 pb; pb.x=f2b(pB[it].x); pb.y=f2b(pB[it].y); pb.z=f2b(pB[it].z); pb.w=f2b(pB[it].w);
            ushort4 pc; pc.x=f2b(pC[it].x); pc.y=f2b(pC[it].y); pc.z=f2b(pC[it].z); pc.w=f2b(pC[it].w);
            ushort4 pd; pd.x=f2b(pD[it].x); pd.y=f2b(pD[it].y); pd.z=f2b(pD[it].z); pd.w=f2b(pD[it].w);
            *(ushort4*)swzp(sm.u.x1, row, 768, 2 * c4)       = pa;
            *(ushort4*)swzp(sm.u.x1, row, 768, 128 + 2 * c4) = pb;
            *(ushort4*)swzp(sm.u.x1, row, 768, 256 + 2 * c4) = pc;
            *(ushort4*)swzp(sm.u.x1, row, 768, 384 + 2 * c4) = pd;
        }
        #pragma unroll
        for (int it = 0; it < 4; ++it) {
            int q   = it * 512 + tid;
            int row = q >> 5;
            int c4  = (q & 31) << 2;
            ushort4 p; p.x=f2b(pH[it].x); p.y=f2b(pH[it].y); p.z=f2b(pH[it].z); p.w=f2b(pH[it].w);
            *(ushort4*)swzp(sm.hbf, row, 256, 2 * c4) = p;
        }
        // winding MLP: Linear(2->128)+LN+ReLU, 8 threads/row (from prefetched pw0/pw1)
        {
            int row = tid >> 3;
            int seg = tid & 7;
            float vals[16]; float s = 0.f, s2 = 0.f;
            #pragma unroll
            for (int j = 0; j < 16; ++j) {
                int jj = seg * 16 + j;
                float v = fmaf(pw0, Ww[2 * jj], fmaf(pw1, Ww[2 * jj + 1], bw[jj]));
                vals[j] = v; s += v; s2 += v * v;
            }
            s  += __shfl_xor(s, 1);  s  += __shfl_xor(s, 2);  s  += __shfl_xor(s, 4);
            s2 += __shfl_xor(s2, 1); s2 += __shfl_xor(s2, 2); s2 += __shfl_xor(s2, 4);
            float mean = s * (1.f / 128.f);
            float var  = fmaxf(s2 * (1.f / 128.f) - mean * mean, 0.f);
            float inv  = rsqrtf(var + 1e-5f);
            #pragma unroll
            for (int j4 = 0; j4 < 4; ++j4) {
                ushort4 pk;
                #pragma unroll
                for (int j = 0; j < 4; ++j) {
                    int jj = seg * 16 + j4 * 4 + j;
                    float v = (vals[j4 * 4 + j] - mean) * inv * gw[jj] + betaw[jj];
                    ((unsigned short*)&pk)[j] = f2b(fmaxf(v, 0.f));
                }
                *(ushort4*)swzp(sm.u.x1, row, 768, 512 + seg * 32 + j4 * 8) = pk;
            }
        }
        lbar();   // (1) staging complete

        // issue next tile's prefetch; consumed only at next iteration's Phase A,
        // so the whole tile compute hides the HBM latency (no vmcnt drain at lbar).
        {
            int tn = tile + NBLOCKS;
            issue_loads(tn < NTILES ? tn : tile);
        }

        // ---------------- GEMM1 (transposed): acc = W1slice @ x1^T ----------------
        f32x4 acc[4];
        #pragma unroll
        for (int mt = 0; mt < 4; ++mt) acc[mt] = (f32x4){0.f, 0.f, 0.f, 0.f};
        {
            const unsigned short* wp = W1bf + (size_t)wrow * 384 + lhi * 8;
            #pragma unroll
            for (int ks = 0; ks < 12; ++ks) {
                bf16x8 wf = *(const bf16x8*)(wp + ks * 32);
                #pragma unroll
                for (int mt = 0; mt < 4; ++mt) {
                    bf16x8 xf = *(const bf16x8*)swzp(sm.u.x1, mt * 16 + llo, 768, ks * 64 + lhi * 16);
                    acc[mt] = MFMA(wf, xf, acc[mt]);
                }
            }
        }
        {   // bias + per-wave LN partials (shfl across lhi)
            #pragma unroll
            for (int mt = 0; mt < 4; ++mt) {
                float s  = 0.f, s2 = 0.f;
                #pragma unroll
                for (int r = 0; r < 4; ++r) {
                    float v = acc[mt][r] + ((const float*)&b1q)[r];
                    acc[mt][r] = v; s += v; s2 += v * v;
                }
                s  += __shfl_xor(s, 16);  s  += __shfl_xor(s, 32);
                s2 += __shfl_xor(s2, 16); s2 += __shfl_xor(s2, 32);
                if (lane < 16) { sm.lns[mt * 16 + llo][wave] = s; sm.ln2[mt * 16 + llo][wave] = s2; }
            }
        }
        lbar();   // (2) x1 reads done + LN partials ready -> y may alias x1

        {   // LN apply + ReLU + packed y write
            #pragma unroll
            for (int mt = 0; mt < 4; ++mt) {
                int edge = mt * 16 + llo;
                float4 sa = *(const float4*)&sm.lns[edge][0];
                float4 sb = *(const float4*)&sm.lns[edge][4];
                float4 ta = *(const float4*)&sm.ln2[edge][0];
                float4 tb = *(const float4*)&sm.ln2[edge][4];
                float s  = sa.x + sa.y + sa.z + sa.w + sb.x + sb.y + sb.z + sb.w;
                float s2 = ta.x + ta.y + ta.z + ta.w + tb.x + tb.y + tb.z + tb.w;
                float mean = s * (1.f / 128.f);
                float var  = fmaxf(s2 * (1.f / 128.f) - mean * mean, 0.f);
                float inv  = rsqrtf(var + 1e-5f);
                ushort4 pk;
                #pragma unroll
                for (int r = 0; r < 4; ++r) {
                    float v = (acc[mt][r] - mean) * inv * ((const float*)&g1q)[r] + ((const float*)&be1q)[r];
                    ((unsigned short*)&pk)[r] = f2b(fmaxf(v, 0.f));
                }
                *(ushort4*)swzp(sm.u.p.y, edge, 256, 2 * fb) = pk;
            }
        }
        lbar();   // (3) y complete

        // ---------------- GRU (transposed), two 32-edge halves ----------------
        {
            const unsigned short* pi = Wihbf + (size_t)wrow * 128 + lhi * 8;
            const unsigned short* ph = Whhbf + (size_t)wrow * 128 + lhi * 8;
            #pragma unroll
            for (int mh = 0; mh < 2; ++mh) {
                f32x4 gr[2], gz[2], gn[2], gh[2];
                #pragma unroll
                for (int m = 0; m < 2; ++m) {
                    gr[m] = (f32x4){0.f,0.f,0.f,0.f}; gz[m] = (f32x4){0.f,0.f,0.f,0.f};
                    gn[m] = (f32x4){0.f,0.f,0.f,0.f}; gh[m] = (f32x4){0.f,0.f,0.f,0.f};
                }
                #pragma unroll
                for (int ks = 0; ks < 4; ++ks) {
                    bf16x8 wr_ = *(const bf16x8*)(pi + ks * 32);
                    bf16x8 wz_ = *(const bf16x8*)(pi + 128 * 128 + ks * 32);
                    bf16x8 wn_ = *(const bf16x8*)(pi + 256 * 128 + ks * 32);
                    bf16x8 vr_ = *(const bf16x8*)(ph + ks * 32);
                    bf16x8 vz_ = *(const bf16x8*)(ph + 128 * 128 + ks * 32);
                    bf16x8 vn_ = *(const bf16x8*)(ph + 256 * 128 + ks * 32);
                    #pragma unroll
                    for (int m = 0; m < 2; ++m) {
                        int er = (mh * 2 + m) * 16 + llo;
                        bf16x8 ay = *(const bf16x8*)swzp(sm.u.p.y, er, 256, ks * 64 + lhi * 16);
                        bf16x8 ah = *(const bf16x8*)swzp(sm.hbf,   er, 256, ks * 64 + lhi * 16);
                        gr[m] = MFMA(wr_, ay, gr[m]);  gr[m] = MFMA(vr_, ah, gr[m]);
                        gz[m] = MFMA(wz_, ay, gz[m]);  gz[m] = MFMA(vz_, ah, gz[m]);
                        gn[m] = MFMA(wn_, ay, gn[m]);  gh[m] = MFMA(vn_, ah, gh[m]);
                    }
                }
                #pragma unroll
                for (int m = 0; m < 2; ++m) {
                    int edge = (mh * 2 + m) * 16 + llo;
                    ushort4 hp = *(const ushort4*)swzp(sm.hbf, edge, 256, 2 * fb);
                    ushort4 pk;
                    #pragma unroll
                    for (int r = 0; r < 4; ++r) {
                        float rr = sigm(gr[m][r] + ((const float*)&biq0)[r] + ((const float*)&bhq0)[r]);
                        float zz = sigm(gz[m][r] + ((const float*)&biq1)[r] + ((const float*)&bhq1)[r]);
                        float nn = tanh_fast(gn[m][r] + ((const float*)&biq2)[r]
                                             + rr * (gh[m][r] + ((const float*)&bhq2)[r]));
                        float hv = b2f(((const unsigned short*)&hp)[r]);
                        float hnv = (1.f - zz) * nn + zz * hv;
                        ((unsigned short*)&pk)[r] = f2b(hnv);
                    }
                    *(ushort4*)swzp(sm.u.p.hnew, edge, 256, 2 * fb) = pk;
                }
            }
        }
        lbar();   // (4) hnew complete; y dead -> xo may alias y

        // ---------------- GEMM3 (waves 0-3) + hout copy (waves 4-7) ----------------
        if (wave < 4) {
            f32x4 a3[4];
            #pragma unroll
            for (int m = 0; m < 4; ++m) a3[m] = (f32x4){0.f, 0.f, 0.f, 0.f};
            const unsigned short* px = Wxbf + (size_t)wrow * 128 + lhi * 8;
            #pragma unroll
            for (int ks = 0; ks < 4; ++ks) {
                bf16x8 wf = *(const bf16x8*)(px + ks * 32);
                #pragma unroll
                for (int m = 0; m < 4; ++m) {
                    bf16x8 bh = *(const bf16x8*)swzp(sm.u.p.hnew, m * 16 + llo, 256, ks * 64 + lhi * 16);
                    a3[m] = MFMA(wf, bh, a3[m]);
                }
            }
            #pragma unroll
            for (int m = 0; m < 4; ++m) {
                float4 o;
                o.x = a3[m][0] + bxq.x; o.y = a3[m][1] + bxq.y;
                o.z = a3[m][2] + bxq.z; o.w = a3[m][3] + bxq.w;
                *(float4*)swzp(sm.u.xo, m * 16 + llo, 256, 4 * fb) = o;
            }
        } else {
            // hout copy: per i, lanes cover consecutive 64B chunks (full sectors)
            int t2  = tid - 256;
            int row = t2 >> 2;
            size_t e = e0 + row;
            #pragma unroll
            for (int i = 0; i < 8; ++i) {
                ushort4 v = *(const ushort4*)swzp(sm.u.p.hnew, row, 256, (t2 & 3) * 8 + 32 * i);
                if (e < E_TOTAL) {
                    float4 f;
                    f.x = b2f(v.x); f.y = b2f(v.y); f.z = b2f(v.z); f.w = b2f(v.w);
                    *(float4*)(hout + e * 128 + (t2 & 3) * 4 + 16 * i) = f;
                }
            }
        }
        lbar();   // (5) xo complete

        {   // xout write: all 512 threads, consecutive lanes -> consecutive 16B
            int row = tid >> 3;
            size_t e = e0 + row;
            if (e < E_TOTAL) {
                #pragma unroll
                for (int i = 0; i < 2; ++i) {
                    float4 v = *(const float4*)swzp(sm.u.xo, row, 256, (tid & 7) * 16 + 128 * i);
                    *(float4*)(xout + e * 64 + (tid & 7) * 4 + 32 * i) = v;
                }
            }
        }
        lbar();   // (6) xo reads done -> next tile may overwrite
    }
}

extern "C" void kernel_launch(void* const* d_in, const int* in_sizes, int n_in,
                              void* d_out, int out_size, void* d_ws, size_t ws_size,
                              hipStream_t stream)
{
    const float* src   = (const float*)d_in[0];
    const float* dst   = (const float*)d_in[1];
    const float* eat   = (const float*)d_in[2];
    const float* hin   = (const float*)d_in[3];
    const float* u     = (const float*)d_in[4];
    const int*   bat   = (const int*)d_in[5];
    const float* wind  = (const float*)d_in[6];
    const float* Ww    = (const float*)d_in[7];
    const float* bw    = (const float*)d_in[8];
    const float* gw    = (const float*)d_in[9];
    const float* betaw = (const float*)d_in[10];
    const float* W1    = (const float*)d_in[11];
    const float* b1    = (const float*)d_in[12];
    const float* g1    = (const float*)d_in[13];
    const float* beta1 = (const float*)d_in[14];
    const float* Wih   = (const float*)d_in[15];
    const float* Whh   = (const float*)d_in[16];
    const float* bih   = (const float*)d_in[17];
    const float* bhh   = (const float*)d_in[18];
    const float* Wx    = (const float*)d_in[19];
    const float* bx    = (const float*)d_in[20];

    unsigned short* wbuf = (unsigned short*)d_ws;   // 155648 bf16 = 304 KB
    wconv_kernel<<<608, 256, 0, stream>>>(W1, Wih, Whh, Wx, wbuf);

    float* xout = (float*)d_out;
    float* hout = xout + (size_t)E_TOTAL * 64;
    edge_model_kernel<<<NBLOCKS, 512, 0, stream>>>(
        src, dst, eat, hin, u, bat, wind, Ww, bw, gw, betaw,
        b1, g1, beta1, bih, bhh, bx,
        wbuf, wbuf + 49152, wbuf + 98304, wbuf + 147456,
        xout, hout);
}

// Round 8
// 1060.800 us; speedup vs baseline: 1.3050x; 1.3050x over previous
//
#include <hip/hip_runtime.h>
#include <hip/hip_bf16.h>

#define E_TOTAL 500000
#define NTILES ((E_TOTAL + 63) / 64)   // 7813
#define NBLOCKS 512

typedef __attribute__((ext_vector_type(8))) short bf16x8;
typedef __attribute__((ext_vector_type(4))) float f32x4;

// D = A*B + C ; A rows -> C rows (features), B cols -> C cols (edges)
#define MFMA(a, b, c) __builtin_amdgcn_mfma_f32_16x16x32_bf16((a), (b), (c), 0, 0, 0)

// Barrier with LDS-only drain: leaves global loads/stores in flight (T4 essence).
// Correct because all intra-block communication goes through LDS (lgkm ops);
// compiler still inserts vmcnt waits for data deps on global loads.
__device__ __forceinline__ void lbar() {
    asm volatile("s_waitcnt lgkmcnt(0)" ::: "memory");
    __builtin_amdgcn_s_barrier();
}

__device__ __forceinline__ unsigned short f2b(float f) {
    return __builtin_bit_cast(unsigned short, __float2bfloat16(f));
}
__device__ __forceinline__ float b2f(unsigned short s) {
    return __bfloat162float(__builtin_bit_cast(__hip_bfloat16, s));
}
__device__ __forceinline__ float sigm(float x) { return 1.f / (1.f + __expf(-x)); }
__device__ __forceinline__ float tanh_fast(float x) {
    float t = __expf(-2.f * x);
    return (1.f - t) / (1.f + t);
}
// XOR-swizzled LDS address (T2): spreads 8 consecutive rows over 8 16B slots.
__device__ __forceinline__ char* swzp(void* base, int row, int rowBytes, int colByte) {
    return (char*)base + row * rowBytes + (colByte ^ ((row & 7) << 4));
}

// f32 -> bf16 weight pre-conversion into workspace (runs every call; cheap).
__global__ void wconv_kernel(const float* __restrict__ W1, const float* __restrict__ Wih,
                             const float* __restrict__ Whh, const float* __restrict__ Wx,
                             unsigned short* __restrict__ out) {
    int i = blockIdx.x * 256 + threadIdx.x;
    if (i >= 155648) return;
    float v;
    if      (i < 49152)  v = W1[i];
    else if (i < 98304)  v = Wih[i - 49152];
    else if (i < 147456) v = Whh[i - 98304];
    else                 v = Wx[i - 147456];
    out[i] = f2b(v);
}

// LDS 71680 B. All tiles XOR-swizzled, pad-free strides.
struct Smem {
    union {
        unsigned short x1[64][384];                       // 49152, staging -> GEMM1
        struct { unsigned short y[64][128];               // [0,16384)   GEMM1-out -> GRU
                 unsigned short hnew[64][128]; } p;       // [16384,32768) GRU-out -> GEMM3
    } u;
    unsigned short hbf[64][128];                          // 16384, h tile bf16
    float lns[64][12];                                    // 3072
    float ln2[64][12];                                    // 3072
};

__global__ __launch_bounds__(512, 1) void edge_model_kernel(
    const float* __restrict__ src, const float* __restrict__ dst,
    const float* __restrict__ eat, const float* __restrict__ hin,
    const float* __restrict__ u, const int* __restrict__ batch,
    const float* __restrict__ winding,
    const float* __restrict__ Ww, const float* __restrict__ bw,
    const float* __restrict__ gw, const float* __restrict__ betaw,
    const float* __restrict__ b1, const float* __restrict__ g1,
    const float* __restrict__ beta1,
    const float* __restrict__ bih, const float* __restrict__ bhh,
    const float* __restrict__ bx,
    const unsigned short* __restrict__ W1bf, const unsigned short* __restrict__ Wihbf,
    const unsigned short* __restrict__ Whhbf, const unsigned short* __restrict__ Wxbf,
    float* __restrict__ xout, float* __restrict__ hout)
{
    __shared__ Smem sm;
    const int tid  = threadIdx.x;
    const int wave = tid >> 6;        // 0..7; owns FEATURE rows [16w,16w+16) in GEMM1/GRU
    const int lane = tid & 63;
    const int lhi  = lane >> 4;       // 0..3
    const int llo  = lane & 15;       // 0..15
    const int fb   = wave * 16 + lhi * 4;   // 4-feature base (feature = fb + r)
    const int wrow = wave * 16 + llo;       // weight row for A-fragments

    // GEMM3 mapping: all 8 waves; (wave&3) picks feature group, wave>>2 picks edge half
    const int fbx   = (wave & 3) * 16 + lhi * 4;
    const int wrowx = (wave & 3) * 16 + llo;
    const int moff  = (wave >> 2) * 2;

    // ---- loop-invariant params hoisted to registers ----
    const float4 b1q  = *(const float4*)&b1[fb];
    const float4 g1q  = *(const float4*)&g1[fb];
    const float4 be1q = *(const float4*)&beta1[fb];
    const float4 biq0 = *(const float4*)&bih[fb];
    const float4 biq1 = *(const float4*)&bih[128 + fb];
    const float4 biq2 = *(const float4*)&bih[256 + fb];
    const float4 bhq0 = *(const float4*)&bhh[fb];
    const float4 bhq1 = *(const float4*)&bhh[128 + fb];
    const float4 bhq2 = *(const float4*)&bhh[256 + fb];
    const float4 bxq  = *(const float4*)&bx[fbx];

    for (int tile = blockIdx.x; tile < NTILES; tile += NBLOCKS) {
        const size_t e0 = (size_t)tile * 64;

        // ---------------- Phase A: stage x1 cols 0..255 and h tile (swizzled) ----------------
        #pragma unroll
        for (int it = 0; it < 2; ++it) {
            int q   = it * 512 + tid;            // 1024 float4-quads
            int row = q >> 4;
            int c4  = (q & 15) << 2;
            size_t e = e0 + row; if (e >= E_TOTAL) e = E_TOTAL - 1;
            float4 a = *(const float4*)(src + e * 64 + c4);
            float4 b = *(const float4*)(dst + e * 64 + c4);
            float4 c = *(const float4*)(eat + e * 64 + c4);
            int bi   = batch[e];
            float4 d = *(const float4*)(u + (size_t)bi * 64 + c4);
            ushort4 pa; pa.x=f2b(a.x); pa.y=f2b(a.y); pa.z=f2b(a.z); pa.w=f2b(a.w);
            ushort4 pb; pb.x=f2b(b.x); pb.y=f2b(b.y); pb.z=f2b(b.z); pb.w=f2b(b.w);
            ushort4 pc; pc.x=f2b(c.x); pc.y=f2b(c.y); pc.z=f2b(c.z); pc.w=f2b(c.w);
            ushort4 pd; pd.x=f2b(d.x); pd.y=f2b(d.y); pd.z=f2b(d.z); pd.w=f2b(d.w);
            *(ushort4*)swzp(sm.u.x1, row, 768, 2 * c4)       = pa;
            *(ushort4*)swzp(sm.u.x1, row, 768, 128 + 2 * c4) = pb;
            *(ushort4*)swzp(sm.u.x1, row, 768, 256 + 2 * c4) = pc;
            *(ushort4*)swzp(sm.u.x1, row, 768, 384 + 2 * c4) = pd;
        }
        #pragma unroll
        for (int it = 0; it < 4; ++it) {
            int q   = it * 512 + tid;            // 2048 float4-quads
            int row = q >> 5;
            int c4  = (q & 31) << 2;
            size_t e = e0 + row; if (e >= E_TOTAL) e = E_TOTAL - 1;
            float4 v = *(const float4*)(hin + e * 128 + c4);
            ushort4 p; p.x=f2b(v.x); p.y=f2b(v.y); p.z=f2b(v.z); p.w=f2b(v.w);
            *(ushort4*)swzp(sm.hbf, row, 256, 2 * c4) = p;
        }
        // winding MLP: Linear(2->128)+LN+ReLU, 8 threads/row
        {
            int row = tid >> 3;
            int seg = tid & 7;
            size_t e = e0 + row; if (e >= E_TOTAL) e = E_TOTAL - 1;
            float wi0 = winding[e * 2], wi1 = winding[e * 2 + 1];
            float vals[16]; float s = 0.f, s2 = 0.f;
            #pragma unroll
            for (int j = 0; j < 16; ++j) {
                int jj = seg * 16 + j;
                float v = fmaf(wi0, Ww[2 * jj], fmaf(wi1, Ww[2 * jj + 1], bw[jj]));
                vals[j] = v; s += v; s2 += v * v;
            }
            s  += __shfl_xor(s, 1);  s  += __shfl_xor(s, 2);  s  += __shfl_xor(s, 4);
            s2 += __shfl_xor(s2, 1); s2 += __shfl_xor(s2, 2); s2 += __shfl_xor(s2, 4);
            float mean = s * (1.f / 128.f);
            float var  = fmaxf(s2 * (1.f / 128.f) - mean * mean, 0.f);
            float inv  = rsqrtf(var + 1e-5f);
            #pragma unroll
            for (int j4 = 0; j4 < 4; ++j4) {
                ushort4 pk;
                #pragma unroll
                for (int j = 0; j < 4; ++j) {
                    int jj = seg * 16 + j4 * 4 + j;
                    float v = (vals[j4 * 4 + j] - mean) * inv * gw[jj] + betaw[jj];
                    ((unsigned short*)&pk)[j] = f2b(fmaxf(v, 0.f));
                }
                *(ushort4*)swzp(sm.u.x1, row, 768, 512 + seg * 32 + j4 * 8) = pk;
            }
        }
        lbar();   // (1) staging complete

        // ---------------- GEMM1 (transposed): acc = W1slice @ x1^T ----------------
        f32x4 acc[4];
        #pragma unroll
        for (int mt = 0; mt < 4; ++mt) acc[mt] = (f32x4){0.f, 0.f, 0.f, 0.f};
        {
            const unsigned short* wp = W1bf + (size_t)wrow * 384 + lhi * 8;
            #pragma unroll
            for (int ks = 0; ks < 12; ++ks) {
                bf16x8 wf = *(const bf16x8*)(wp + ks * 32);
                #pragma unroll
                for (int mt = 0; mt < 4; ++mt) {
                    bf16x8 xf = *(const bf16x8*)swzp(sm.u.x1, mt * 16 + llo, 768, ks * 64 + lhi * 16);
                    acc[mt] = MFMA(wf, xf, acc[mt]);
                }
            }
        }
        {   // bias + per-wave LN partials (shfl across lhi)
            #pragma unroll
            for (int mt = 0; mt < 4; ++mt) {
                float s  = 0.f, s2 = 0.f;
                #pragma unroll
                for (int r = 0; r < 4; ++r) {
                    float v = acc[mt][r] + ((const float*)&b1q)[r];
                    acc[mt][r] = v; s += v; s2 += v * v;
                }
                s  += __shfl_xor(s, 16);  s  += __shfl_xor(s, 32);
                s2 += __shfl_xor(s2, 16); s2 += __shfl_xor(s2, 32);
                if (lane < 16) { sm.lns[mt * 16 + llo][wave] = s; sm.ln2[mt * 16 + llo][wave] = s2; }
            }
        }
        lbar();   // (2) x1 reads done + LN partials ready -> y may alias x1

        {   // LN apply + ReLU + packed y write
            #pragma unroll
            for (int mt = 0; mt < 4; ++mt) {
                int edge = mt * 16 + llo;
                float4 sa = *(const float4*)&sm.lns[edge][0];
                float4 sb = *(const float4*)&sm.lns[edge][4];
                float4 ta = *(const float4*)&sm.ln2[edge][0];
                float4 tb = *(const float4*)&sm.ln2[edge][4];
                float s  = sa.x + sa.y + sa.z + sa.w + sb.x + sb.y + sb.z + sb.w;
                float s2 = ta.x + ta.y + ta.z + ta.w + tb.x + tb.y + tb.z + tb.w;
                float mean = s * (1.f / 128.f);
                float var  = fmaxf(s2 * (1.f / 128.f) - mean * mean, 0.f);
                float inv  = rsqrtf(var + 1e-5f);
                ushort4 pk;
                #pragma unroll
                for (int r = 0; r < 4; ++r) {
                    float v = (acc[mt][r] - mean) * inv * ((const float*)&g1q)[r] + ((const float*)&be1q)[r];
                    ((unsigned short*)&pk)[r] = f2b(fmaxf(v, 0.f));
                }
                *(ushort4*)swzp(sm.u.p.y, edge, 256, 2 * fb) = pk;
            }
        }
        lbar();   // (3) y complete

        // ---------------- GRU (transposed), two 32-edge halves; direct hout stores ----------------
        {
            const unsigned short* pi = Wihbf + (size_t)wrow * 128 + lhi * 8;
            const unsigned short* ph = Whhbf + (size_t)wrow * 128 + lhi * 8;
            #pragma unroll
            for (int mh = 0; mh < 2; ++mh) {
                f32x4 gr[2], gz[2], gn[2], gh[2];
                #pragma unroll
                for (int m = 0; m < 2; ++m) {
                    gr[m] = (f32x4){0.f,0.f,0.f,0.f}; gz[m] = (f32x4){0.f,0.f,0.f,0.f};
                    gn[m] = (f32x4){0.f,0.f,0.f,0.f}; gh[m] = (f32x4){0.f,0.f,0.f,0.f};
                }
                #pragma unroll
                for (int ks = 0; ks < 4; ++ks) {
                    bf16x8 wr_ = *(const bf16x8*)(pi + ks * 32);
                    bf16x8 wz_ = *(const bf16x8*)(pi + 128 * 128 + ks * 32);
                    bf16x8 wn_ = *(const bf16x8*)(pi + 256 * 128 + ks * 32);
                    bf16x8 vr_ = *(const bf16x8*)(ph + ks * 32);
                    bf16x8 vz_ = *(const bf16x8*)(ph + 128 * 128 + ks * 32);
                    bf16x8 vn_ = *(const bf16x8*)(ph + 256 * 128 + ks * 32);
                    #pragma unroll
                    for (int m = 0; m < 2; ++m) {
                        int er = (mh * 2 + m) * 16 + llo;
                        bf16x8 ay = *(const bf16x8*)swzp(sm.u.p.y, er, 256, ks * 64 + lhi * 16);
                        bf16x8 ah = *(const bf16x8*)swzp(sm.hbf,   er, 256, ks * 64 + lhi * 16);
                        gr[m] = MFMA(wr_, ay, gr[m]);  gr[m] = MFMA(vr_, ah, gr[m]);
                        gz[m] = MFMA(wz_, ay, gz[m]);  gz[m] = MFMA(vz_, ah, gz[m]);
                        gn[m] = MFMA(wn_, ay, gn[m]);  gh[m] = MFMA(vn_, ah, gh[m]);
                    }
                }
                #pragma unroll
                for (int m = 0; m < 2; ++m) {
                    int edge = (mh * 2 + m) * 16 + llo;
                    ushort4 hp = *(const ushort4*)swzp(sm.hbf, edge, 256, 2 * fb);
                    ushort4 pk;
                    float4  ho;
                    #pragma unroll
                    for (int r = 0; r < 4; ++r) {
                        float rr = sigm(gr[m][r] + ((const float*)&biq0)[r] + ((const float*)&bhq0)[r]);
                        float zz = sigm(gz[m][r] + ((const float*)&biq1)[r] + ((const float*)&bhq1)[r]);
                        float nn = tanh_fast(gn[m][r] + ((const float*)&biq2)[r]
                                             + rr * (gh[m][r] + ((const float*)&bhq2)[r]));
                        float hv = b2f(((const unsigned short*)&hp)[r]);
                        float hnv = (1.f - zz) * nn + zz * hv;
                        ((unsigned short*)&pk)[r] = f2b(hnv);
                        ((float*)&ho)[r] = hnv;
                    }
                    *(ushort4*)swzp(sm.u.p.hnew, edge, 256, 2 * fb) = pk;
                    size_t e = e0 + edge;   // direct store: 4-lane lhi group covers 64B sector
                    if (e < E_TOTAL) *(float4*)(hout + e * 128 + fb) = ho;
                }
            }
        }
        lbar();   // (4) hnew complete

        // ---------------- GEMM3 on all 8 waves (2 edge-groups each); direct xout stores ----------------
        {
            f32x4 a3[2];
            a3[0] = (f32x4){0.f, 0.f, 0.f, 0.f};
            a3[1] = (f32x4){0.f, 0.f, 0.f, 0.f};
            const unsigned short* px = Wxbf + (size_t)wrowx * 128 + lhi * 8;
            #pragma unroll
            for (int ks = 0; ks < 4; ++ks) {
                bf16x8 wf = *(const bf16x8*)(px + ks * 32);
                #pragma unroll
                for (int m = 0; m < 2; ++m) {
                    bf16x8 bh = *(const bf16x8*)swzp(sm.u.p.hnew, (moff + m) * 16 + llo, 256, ks * 64 + lhi * 16);
                    a3[m] = MFMA(wf, bh, a3[m]);
                }
            }
            #pragma unroll
            for (int m = 0; m < 2; ++m) {
                int edge = (moff + m) * 16 + llo;
                float4 o;
                o.x = a3[m][0] + bxq.x; o.y = a3[m][1] + bxq.y;
                o.z = a3[m][2] + bxq.z; o.w = a3[m][3] + bxq.w;
                size_t e = e0 + edge;   // direct store: 4-lane lhi group covers 64B sector
                if (e < E_TOTAL) *(float4*)(xout + e * 64 + fbx) = o;
            }
        }
        lbar();   // (5) hnew reads done -> next tile may overwrite x1 region
    }
}

extern "C" void kernel_launch(void* const* d_in, const int* in_sizes, int n_in,
                              void* d_out, int out_size, void* d_ws, size_t ws_size,
                              hipStream_t stream)
{
    const float* src   = (const float*)d_in[0];
    const float* dst   = (const float*)d_in[1];
    const float* eat   = (const float*)d_in[2];
    const float* hin   = (const float*)d_in[3];
    const float* u     = (const float*)d_in[4];
    const int*   bat   = (const int*)d_in[5];
    const float* wind  = (const float*)d_in[6];
    const float* Ww    = (const float*)d_in[7];
    const float* bw    = (const float*)d_in[8];
    const float* gw    = (const float*)d_in[9];
    const float* betaw = (const float*)d_in[10];
    const float* W1    = (const float*)d_in[11];
    const float* b1    = (const float*)d_in[12];
    const float* g1    = (const float*)d_in[13];
    const float* beta1 = (const float*)d_in[14];
    const float* Wih   = (const float*)d_in[15];
    const float* Whh   = (const float*)d_in[16];
    const float* bih   = (const float*)d_in[17];
    const float* bhh   = (const float*)d_in[18];
    const float* Wx    = (const float*)d_in[19];
    const float* bx    = (const float*)d_in[20];

    unsigned short* wbuf = (unsigned short*)d_ws;   // 155648 bf16 = 304 KB
    wconv_kernel<<<608, 256, 0, stream>>>(W1, Wih, Whh, Wx, wbuf);

    float* xout = (float*)d_out;
    float* hout = xout + (size_t)E_TOTAL * 64;
    edge_model_kernel<<<NBLOCKS, 512, 0, stream>>>(
        src, dst, eat, hin, u, bat, wind, Ww, bw, gw, betaw,
        b1, g1, beta1, bih, bhh, bx,
        wbuf, wbuf + 49152, wbuf + 98304, wbuf + 147456,
        xout, hout);
}